// Round 1
// baseline (447.087 us; speedup 1.0000x reference)
//
#include <hip/hip_runtime.h>

// PSP: syn_t = syn_{t-1} * (1 - 1/tau) + x_t / tau, tau = 2.0 → syn = 0.5*(syn + x)
// Shapes: inputs (T=64, N=512, C=2048) f32, output same. Scan is serial in T,
// independent per (n,c). One thread owns 4 contiguous channels (float4).

#define T_STEPS 64
#define NC (512 * 2048)        // 1048576 channels
#define NC4 (NC / 4)           // 262144 float4 lanes

__global__ __launch_bounds__(256) void psp_scan_kernel(
    const float4* __restrict__ in, float4* __restrict__ out) {
    const int idx = blockIdx.x * blockDim.x + threadIdx.x;  // [0, NC4)
    const float4* ip = in + idx;
    float4* op = out + idx;

    float sx = 0.f, sy = 0.f, sz = 0.f, sw = 0.f;
#pragma unroll 8
    for (int t = 0; t < T_STEPS; ++t) {
        const float4 x = ip[(size_t)t * NC4];
        sx = 0.5f * (sx + x.x);
        sy = 0.5f * (sy + x.y);
        sz = 0.5f * (sz + x.z);
        sw = 0.5f * (sw + x.w);
        op[(size_t)t * NC4] = make_float4(sx, sy, sz, sw);
    }
}

extern "C" void kernel_launch(void* const* d_in, const int* in_sizes, int n_in,
                              void* d_out, int out_size, void* d_ws, size_t ws_size,
                              hipStream_t stream) {
    const float4* in = (const float4*)d_in[0];
    float4* out = (float4*)d_out;
    // NC4 = 262144 threads → 1024 blocks of 256 (exact fit, no bounds check needed)
    psp_scan_kernel<<<NC4 / 256, 256, 0, stream>>>(in, out);
}